// Round 6
// baseline (52.114 us; speedup 1.0000x reference)
//
#include <hip/hip_runtime.h>
#include <math.h>

#define HH 1024
#define VV 50257
#define NLB 2048           // logits blocks
#define NWAVE (NLB * 4)    // 8192 logits waves; 50257 = 6*8192 + 1105
#define NTAIL (VV - 6 * NWAVE)  // 1105

__device__ __forceinline__ float wave_allreduce_sum(float v) {
#pragma unroll
    for (int off = 1; off < 64; off <<= 1) v += __shfl_xor(v, off, 64);
    return v;
}

__device__ __forceinline__ void lse_comb(float& m, float& s, float om, float os) {
    float M = fmaxf(m, om);
    s = s * __expf(m - M) + os * __expf(om - M);
    m = M;
}

__device__ __forceinline__ float sigmoidf(float x) { return 1.0f / (1.0f + __expf(-x)); }

__device__ __forceinline__ float dot4(float4 a, float4 b) {
    return a.x * b.x + a.y * b.y + a.z * b.z + a.w * b.w;
}

// Kernel 1: fused gates+cell. 1024 blocks x 512 threads, VGPR capped so all
// 4 blocks/CU (32 waves/CU) are co-resident immediately.
__global__ __launch_bounds__(512, 8) void k_gatecell(
    const int* __restrict__ x, const float* __restrict__ emb,
    const float* __restrict__ h0, const float* __restrict__ c0,
    const float* __restrict__ w_ih, const float* __restrict__ w_hh,
    const float* __restrict__ b_ih, const float* __restrict__ b_hh,
    float* __restrict__ out) {
    __shared__ float sg2[8];
    const int j = blockIdx.x;
    const int w = threadIdx.x >> 6;
    const int lane = threadIdx.x & 63;
    const int g = w >> 1, hf = w & 1;
    const int row = g * HH + j;
    const int base = hf * 512 + lane * 8;

    const float* e  = emb + (size_t)x[0] * HH + base;
    const float* wi = w_ih + (size_t)row * HH + base;
    const float* wh = w_hh + (size_t)row * HH + base;
    const float* hp = h0 + base;

    float4 wi0 = *reinterpret_cast<const float4*>(wi);
    float4 wi1 = *reinterpret_cast<const float4*>(wi + 4);
    float4 wh0 = *reinterpret_cast<const float4*>(wh);
    float4 wh1 = *reinterpret_cast<const float4*>(wh + 4);
    float4 e0  = *reinterpret_cast<const float4*>(e);
    float4 e1  = *reinterpret_cast<const float4*>(e + 4);
    float4 hv0 = *reinterpret_cast<const float4*>(hp);
    float4 hv1 = *reinterpret_cast<const float4*>(hp + 4);
    e0.x = fmaxf(e0.x, 0.f); e0.y = fmaxf(e0.y, 0.f);
    e0.z = fmaxf(e0.z, 0.f); e0.w = fmaxf(e0.w, 0.f);
    e1.x = fmaxf(e1.x, 0.f); e1.y = fmaxf(e1.y, 0.f);
    e1.z = fmaxf(e1.z, 0.f); e1.w = fmaxf(e1.w, 0.f);

    float acc = dot4(wi0, e0) + dot4(wi1, e1) + dot4(wh0, hv0) + dot4(wh1, hv1);
    acc = wave_allreduce_sum(acc);
    if (lane == 0)
        sg2[w] = acc + (hf == 0 ? b_ih[row] + b_hh[row] : 0.0f);
    __syncthreads();
    if (threadIdx.x == 0) {
        float ig = sigmoidf(sg2[0] + sg2[1]);
        float fg = sigmoidf(sg2[2] + sg2[3]);
        float gg = tanhf(sg2[4] + sg2[5]);
        float og = sigmoidf(sg2[6] + sg2[7]);
        float c = fg * c0[j] + ig * gg;
        float h = og * tanhf(c);
        out[VV + j] = h;
        out[VV + HH + j] = c;
    }
}

// Kernel 2: logits + fused per-block online LSE. Wave per row, single row at
// a time with a software double-buffer (prefetch row c+1 during row c's
// reduce). Register-lean; VGPR capped for 8 blocks/CU co-residency.
__global__ __launch_bounds__(256, 8) void k_logits_lse(
    const float* __restrict__ w_out, const float* __restrict__ b_out,
    const float* __restrict__ h, float* __restrict__ logits,
    float* __restrict__ pm, float* __restrict__ ps) {
    __shared__ float sm[4], ss[4];
    const int w = threadIdx.x >> 6;
    const int lane = threadIdx.x & 63;
    const int wid = blockIdx.x * 4 + w;
    const bool has7 = (wid < NTAIL);

    // hoist h into 16 VGPRs
    const float* hp = h + lane * 4;
    float4 h0v = *reinterpret_cast<const float4*>(hp);
    float4 h1v = *reinterpret_cast<const float4*>(hp + 256);
    float4 h2v = *reinterpret_cast<const float4*>(hp + 512);
    float4 h3v = *reinterpret_cast<const float4*>(hp + 768);

    const float* wb = w_out + (size_t)wid * HH + lane * 4;
    float m = -1e30f, s = 0.0f;

    // prime: load row chunk 0
    float4 n0 = *reinterpret_cast<const float4*>(wb);
    float4 n1 = *reinterpret_cast<const float4*>(wb + 256);
    float4 n2 = *reinterpret_cast<const float4*>(wb + 512);
    float4 n3 = *reinterpret_cast<const float4*>(wb + 768);

#pragma unroll
    for (int c = 0; c < 6; ++c) {
        float4 a0 = n0, a1 = n1, a2 = n2, a3 = n3;
        if (c < 5 || has7) {  // prefetch next row
            const float* pn = wb + (size_t)(c + 1) * NWAVE * HH;
            n0 = *reinterpret_cast<const float4*>(pn);
            n1 = *reinterpret_cast<const float4*>(pn + 256);
            n2 = *reinterpret_cast<const float4*>(pn + 512);
            n3 = *reinterpret_cast<const float4*>(pn + 768);
        }
        float acc = dot4(a0, h0v) + dot4(a1, h1v) + dot4(a2, h2v) + dot4(a3, h3v);
        acc = wave_allreduce_sum(acc);
        int row = wid + c * NWAVE;
        float v = acc + b_out[row];
        if (lane == 0) logits[row] = v;
        float M = fmaxf(m, v);                       // branchless wave-uniform LSE
        s = s * __expf(m - M) + __expf(v - M);
        m = M;
    }
    if (has7) {
        float acc = dot4(n0, h0v) + dot4(n1, h1v) + dot4(n2, h2v) + dot4(n3, h3v);
        acc = wave_allreduce_sum(acc);
        int row = wid + 6 * NWAVE;
        float v = acc + b_out[row];
        if (lane == 0) logits[row] = v;
        float M = fmaxf(m, v);
        s = s * __expf(m - M) + __expf(v - M);
        m = M;
    }

    if (lane == 0) { sm[w] = m; ss[w] = s; }
    __syncthreads();
    if (threadIdx.x == 0) {
        float M = sm[0], S = ss[0];
#pragma unroll
        for (int q = 1; q < 4; ++q) lse_comb(M, S, sm[q], ss[q]);
        pm[blockIdx.x] = M;
        ps[blockIdx.x] = S;
    }
}

// Kernel 3: each block redundantly folds the NLB (m,s) pairs -> Z, then
// grid-strides out[v] = logits[v] - Z.
__global__ __launch_bounds__(256) void k_final(
    const float* __restrict__ logits, const float* __restrict__ pm,
    const float* __restrict__ ps, float* __restrict__ out) {
    __shared__ float sm[4], ss[4];
    __shared__ float sZ;
    int tid = threadIdx.x;
    int lane = tid & 63;
    float m = -1e30f, s = 0.0f;
    for (int p = tid; p < NLB; p += 256) {
        lse_comb(m, s, pm[p], ps[p]);
    }
#pragma unroll
    for (int off = 1; off < 64; off <<= 1) {
        float om = __shfl_xor(m, off, 64);
        float os = __shfl_xor(s, off, 64);
        lse_comb(m, s, om, os);
    }
    if (lane == 0) { sm[tid >> 6] = m; ss[tid >> 6] = s; }
    __syncthreads();
    if (tid == 0) {
        float M = sm[0], S = ss[0];
#pragma unroll
        for (int q = 1; q < 4; ++q) lse_comb(M, S, sm[q], ss[q]);
        sZ = M + logf(S);
    }
    __syncthreads();
    float Z = sZ;
    for (int i = blockIdx.x * 256 + tid; i < VV; i += gridDim.x * 256)
        out[i] = logits[i] - Z;
}

extern "C" void kernel_launch(void* const* d_in, const int* in_sizes, int n_in,
                              void* d_out, int out_size, void* d_ws, size_t ws_size,
                              hipStream_t stream) {
    const int*   x     = (const int*)d_in[0];
    const float* h0    = (const float*)d_in[1];
    const float* c0    = (const float*)d_in[2];
    const float* emb   = (const float*)d_in[3];
    const float* w_ih  = (const float*)d_in[4];
    const float* w_hh  = (const float*)d_in[5];
    const float* b_ih  = (const float*)d_in[6];
    const float* b_hh  = (const float*)d_in[7];
    const float* w_out = (const float*)d_in[8];
    const float* b_out = (const float*)d_in[9];
    float* out = (float*)d_out;
    float* ws  = (float*)d_ws;

    float* logits = ws;             // 50257 floats (pad to 50304)
    float* pm     = ws + 50304;     // NLB floats
    float* ps     = pm + NLB;       // NLB floats

    k_gatecell<<<HH, 512, 0, stream>>>(x, emb, h0, c0, w_ih, w_hh, b_ih, b_hh, out);
    k_logits_lse<<<NLB, 256, 0, stream>>>(w_out, b_out, out + VV, logits, pm, ps);
    k_final<<<256, 256, 0, stream>>>(logits, pm, ps, out);
}

// Round 7
// 50.396 us; speedup vs baseline: 1.0341x; 1.0341x over previous
//
#include <hip/hip_runtime.h>
#include <math.h>

#define HH 1024
#define VV 50257
#define NLB 1024            // logits blocks (4 waves each -> 4096 waves)
#define NEXTRA 1105         // 50257 = 4096*12 + 1105 -> waves 0..1104 take 13 rows

__device__ __forceinline__ void lse_comb(float& m, float& s, float om, float os) {
    float M = fmaxf(m, om);
    s = s * __expf(m - M) + os * __expf(om - M);
    m = M;
}

__device__ __forceinline__ float sigmoidf(float x) { return 1.0f / (1.0f + __expf(-x)); }

__device__ __forceinline__ float dot4(float4 a, float4 b) {
    return a.x * b.x + a.y * b.y + a.z * b.z + a.w * b.w;
}

// Kernel 1: fused gates+cell. 1024 blocks x 512 threads (proven 47.4us form).
__global__ __launch_bounds__(512) void k_gatecell(
    const int* __restrict__ x, const float* __restrict__ emb,
    const float* __restrict__ h0, const float* __restrict__ c0,
    const float* __restrict__ w_ih, const float* __restrict__ w_hh,
    const float* __restrict__ b_ih, const float* __restrict__ b_hh,
    float* __restrict__ out) {
    __shared__ float sg2[8];
    const int j = blockIdx.x;
    const int w = threadIdx.x >> 6;
    const int lane = threadIdx.x & 63;
    const int g = w >> 1, hf = w & 1;
    const int row = g * HH + j;
    const int base = hf * 512 + lane * 8;

    const float* e  = emb + (size_t)x[0] * HH + base;
    const float* wi = w_ih + (size_t)row * HH + base;
    const float* wh = w_hh + (size_t)row * HH + base;
    const float* hp = h0 + base;

    float4 wi0 = *reinterpret_cast<const float4*>(wi);
    float4 wi1 = *reinterpret_cast<const float4*>(wi + 4);
    float4 wh0 = *reinterpret_cast<const float4*>(wh);
    float4 wh1 = *reinterpret_cast<const float4*>(wh + 4);
    float4 e0  = *reinterpret_cast<const float4*>(e);
    float4 e1  = *reinterpret_cast<const float4*>(e + 4);
    float4 hv0 = *reinterpret_cast<const float4*>(hp);
    float4 hv1 = *reinterpret_cast<const float4*>(hp + 4);
    e0.x = fmaxf(e0.x, 0.f); e0.y = fmaxf(e0.y, 0.f);
    e0.z = fmaxf(e0.z, 0.f); e0.w = fmaxf(e0.w, 0.f);
    e1.x = fmaxf(e1.x, 0.f); e1.y = fmaxf(e1.y, 0.f);
    e1.z = fmaxf(e1.z, 0.f); e1.w = fmaxf(e1.w, 0.f);

    float acc = dot4(wi0, e0) + dot4(wi1, e1) + dot4(wh0, hv0) + dot4(wh1, hv1);
#pragma unroll
    for (int off = 1; off < 64; off <<= 1) acc += __shfl_xor(acc, off, 64);
    if (lane == 0)
        sg2[w] = acc + (hf == 0 ? b_ih[row] + b_hh[row] : 0.0f);
    __syncthreads();
    if (threadIdx.x == 0) {
        float ig = sigmoidf(sg2[0] + sg2[1]);
        float fg = sigmoidf(sg2[2] + sg2[3]);
        float gg = tanhf(sg2[4] + sg2[5]);
        float og = sigmoidf(sg2[6] + sg2[7]);
        float c = fg * c0[j] + ig * gg;
        float h = og * tanhf(c);
        out[VV + j] = h;
        out[VV + HH + j] = c;
    }
}

// Kernel 2: logits + fused per-block online LSE.
// 1024 blocks x 256 thr, cap 128 VGPR (16 waves/CU, 4 blocks/CU, all resident).
// Wave wid owns 12 (or 13 if wid<1105) CONTIGUOUS rows; pairs processed with a
// 2-pair-ahead rotation (3 pair-buffers) for ~12-16 loads in flight per wave.
__global__ __launch_bounds__(256, 4) void k_logits_lse(
    const float* __restrict__ w_out, const float* __restrict__ b_out,
    const float* __restrict__ h, float* __restrict__ logits,
    float* __restrict__ pm, float* __restrict__ ps) {
    __shared__ float4 hs[256];
    __shared__ float sm[4], ss[4];
    const int tid = threadIdx.x;
    const int w = tid >> 6;
    const int lane = tid & 63;

    hs[tid] = reinterpret_cast<const float4*>(h)[tid];
    __syncthreads();

    const int wid = blockIdx.x * 4 + w;
    const bool extra = (wid < NEXTRA);
    const int base = wid * 12 + (extra ? wid : NEXTRA);
    const float* wp = w_out + (size_t)base * HH + lane * 4;

    float4 A[3][4], B[3][4], T[4];

    // prime: load pairs 0 and 1 into slots 0,1
#pragma unroll
    for (int p = 0; p < 2; ++p) {
        const float* pa = wp + (size_t)(2 * p) * HH;
        const float* pb = pa + HH;
#pragma unroll
        for (int c = 0; c < 4; ++c) {
            A[p][c] = *reinterpret_cast<const float4*>(pa + c * 256);
            B[p][c] = *reinterpret_cast<const float4*>(pb + c * 256);
        }
    }

    float m = -1e30f, s = 0.0f;
#pragma unroll
    for (int k = 0; k < 6; ++k) {
        if (k < 4) {  // prefetch pair k+2 into slot (k+2)%3
            const int sl = (k + 2) % 3;
            const float* pa = wp + (size_t)(2 * (k + 2)) * HH;
            const float* pb = pa + HH;
#pragma unroll
            for (int c = 0; c < 4; ++c) {
                A[sl][c] = *reinterpret_cast<const float4*>(pa + c * 256);
                B[sl][c] = *reinterpret_cast<const float4*>(pb + c * 256);
            }
        } else if (k == 4 && extra) {  // prefetch tail row (base+12)
            const float* pt = wp + (size_t)12 * HH;
#pragma unroll
            for (int c = 0; c < 4; ++c)
                T[c] = *reinterpret_cast<const float4*>(pt + c * 256);
        }
        const int cs = k % 3;
        float accA = 0.0f, accB = 0.0f;
#pragma unroll
        for (int c = 0; c < 4; ++c) {
            float4 hc = hs[lane + c * 64];
            accA += dot4(A[cs][c], hc);
            accB += dot4(B[cs][c], hc);
        }
#pragma unroll
        for (int off = 1; off < 64; off <<= 1) {
            accA += __shfl_xor(accA, off, 64);
            accB += __shfl_xor(accB, off, 64);
        }
        const int rA = base + 2 * k;
        const float vA = accA + b_out[rA];
        const float vB = accB + b_out[rA + 1];
        if (lane == 0) {
            logits[rA] = vA;
            logits[rA + 1] = vB;
        }
        float M = fmaxf(m, vA);
        s = s * __expf(m - M) + __expf(vA - M);
        m = M;
        M = fmaxf(m, vB);
        s = s * __expf(m - M) + __expf(vB - M);
        m = M;
    }
    if (extra) {
        float acc = 0.0f;
#pragma unroll
        for (int c = 0; c < 4; ++c) {
            float4 hc = hs[lane + c * 64];
            acc += dot4(T[c], hc);
        }
#pragma unroll
        for (int off = 1; off < 64; off <<= 1) acc += __shfl_xor(acc, off, 64);
        const int r = base + 12;
        const float v = acc + b_out[r];
        if (lane == 0) logits[r] = v;
        float M = fmaxf(m, v);
        s = s * __expf(m - M) + __expf(v - M);
        m = M;
    }

    if (lane == 0) { sm[w] = m; ss[w] = s; }
    __syncthreads();
    if (tid == 0) {
        float M = sm[0], S = ss[0];
#pragma unroll
        for (int q = 1; q < 4; ++q) lse_comb(M, S, sm[q], ss[q]);
        pm[blockIdx.x] = M;
        ps[blockIdx.x] = S;
    }
}

// Kernel 3: each block redundantly folds the NLB (m,s) pairs -> Z, then
// grid-strides out[v] = logits[v] - Z.
__global__ __launch_bounds__(256) void k_final(
    const float* __restrict__ logits, const float* __restrict__ pm,
    const float* __restrict__ ps, float* __restrict__ out) {
    __shared__ float sm[4], ss[4];
    __shared__ float sZ;
    int tid = threadIdx.x;
    int lane = tid & 63;
    float m = -1e30f, s = 0.0f;
#pragma unroll
    for (int t = 0; t < NLB / 256; ++t) {
        int p = tid + t * 256;
        lse_comb(m, s, pm[p], ps[p]);
    }
#pragma unroll
    for (int off = 1; off < 64; off <<= 1) {
        float om = __shfl_xor(m, off, 64);
        float os = __shfl_xor(s, off, 64);
        lse_comb(m, s, om, os);
    }
    if (lane == 0) { sm[tid >> 6] = m; ss[tid >> 6] = s; }
    __syncthreads();
    if (tid == 0) {
        float M = sm[0], S = ss[0];
#pragma unroll
        for (int q = 1; q < 4; ++q) lse_comb(M, S, sm[q], ss[q]);
        sZ = M + logf(S);
    }
    __syncthreads();
    float Z = sZ;
    for (int i = blockIdx.x * 256 + tid; i < VV; i += gridDim.x * 256)
        out[i] = logits[i] - Z;
}

extern "C" void kernel_launch(void* const* d_in, const int* in_sizes, int n_in,
                              void* d_out, int out_size, void* d_ws, size_t ws_size,
                              hipStream_t stream) {
    const int*   x     = (const int*)d_in[0];
    const float* h0    = (const float*)d_in[1];
    const float* c0    = (const float*)d_in[2];
    const float* emb   = (const float*)d_in[3];
    const float* w_ih  = (const float*)d_in[4];
    const float* w_hh  = (const float*)d_in[5];
    const float* b_ih  = (const float*)d_in[6];
    const float* b_hh  = (const float*)d_in[7];
    const float* w_out = (const float*)d_in[8];
    const float* b_out = (const float*)d_in[9];
    float* out = (float*)d_out;
    float* ws  = (float*)d_ws;

    float* logits = ws;             // 50257 floats (pad to 50304)
    float* pm     = ws + 50304;     // NLB floats
    float* ps     = pm + NLB;       // NLB floats

    k_gatecell<<<HH, 512, 0, stream>>>(x, emb, h0, c0, w_ih, w_hh, b_ih, b_hh, out);
    k_logits_lse<<<NLB, 256, 0, stream>>>(w_out, b_out, out + VV, logits, pm, ps);
    k_final<<<256, 256, 0, stream>>>(logits, pm, ps, out);
}

// Round 8
// 46.080 us; speedup vs baseline: 1.1310x; 1.0937x over previous
//
#include <hip/hip_runtime.h>
#include <math.h>

#define HH 1024
#define VV 50257
#define NLB 2048           // logits blocks
#define NWAVE (NLB * 4)    // 8192 logits waves; 50257 = 6*8192 + 1105
#define NTAIL (VV - 6 * NWAVE)  // 1105

__device__ __forceinline__ void lse_comb(float& m, float& s, float om, float os) {
    float M = fmaxf(m, om);
    s = s * __expf(m - M) + os * __expf(om - M);
    m = M;
}

__device__ __forceinline__ float sigmoidf(float x) { return 1.0f / (1.0f + __expf(-x)); }

__device__ __forceinline__ float dot4(float4 a, float4 b) {
    return a.x * b.x + a.y * b.y + a.z * b.z + a.w * b.w;
}

// Kernel 1: fused gates+cell. 1024 blocks x 512 threads (proven form).
// 8192 waves = exactly 32/CU in one residency round.
__global__ __launch_bounds__(512) void k_gatecell(
    const int* __restrict__ x, const float* __restrict__ emb,
    const float* __restrict__ h0, const float* __restrict__ c0,
    const float* __restrict__ w_ih, const float* __restrict__ w_hh,
    const float* __restrict__ b_ih, const float* __restrict__ b_hh,
    float* __restrict__ out) {
    __shared__ float sg2[8];
    const int j = blockIdx.x;
    const int w = threadIdx.x >> 6;
    const int lane = threadIdx.x & 63;
    const int g = w >> 1, hf = w & 1;
    const int row = g * HH + j;
    const int base = hf * 512 + lane * 8;

    const float* e  = emb + (size_t)x[0] * HH + base;
    const float* wi = w_ih + (size_t)row * HH + base;
    const float* wh = w_hh + (size_t)row * HH + base;
    const float* hp = h0 + base;

    float4 wi0 = *reinterpret_cast<const float4*>(wi);
    float4 wi1 = *reinterpret_cast<const float4*>(wi + 4);
    float4 wh0 = *reinterpret_cast<const float4*>(wh);
    float4 wh1 = *reinterpret_cast<const float4*>(wh + 4);
    float4 e0  = *reinterpret_cast<const float4*>(e);
    float4 e1  = *reinterpret_cast<const float4*>(e + 4);
    float4 hv0 = *reinterpret_cast<const float4*>(hp);
    float4 hv1 = *reinterpret_cast<const float4*>(hp + 4);
    e0.x = fmaxf(e0.x, 0.f); e0.y = fmaxf(e0.y, 0.f);
    e0.z = fmaxf(e0.z, 0.f); e0.w = fmaxf(e0.w, 0.f);
    e1.x = fmaxf(e1.x, 0.f); e1.y = fmaxf(e1.y, 0.f);
    e1.z = fmaxf(e1.z, 0.f); e1.w = fmaxf(e1.w, 0.f);

    float acc = dot4(wi0, e0) + dot4(wi1, e1) + dot4(wh0, hv0) + dot4(wh1, hv1);
#pragma unroll
    for (int off = 1; off < 64; off <<= 1) acc += __shfl_xor(acc, off, 64);
    if (lane == 0)
        sg2[w] = acc + (hf == 0 ? b_ih[row] + b_hh[row] : 0.0f);
    __syncthreads();
    if (threadIdx.x == 0) {
        float ig = sigmoidf(sg2[0] + sg2[1]);
        float fg = sigmoidf(sg2[2] + sg2[3]);
        float gg = tanhf(sg2[4] + sg2[5]);
        float og = sigmoidf(sg2[6] + sg2[7]);
        float c = fg * c0[j] + ig * gg;
        float h = og * tanhf(c);
        out[VV + j] = h;
        out[VV + HH + j] = c;
    }
}

// Kernel 2: logits + fused per-block online LSE. Round-5 pair structure
// (8 dwordx4 in flight per wave) but h lives in LDS and VGPR is capped to 64
// via __launch_bounds__(256,8) -> 32 waves/CU, double the in-flight bytes.
__global__ __launch_bounds__(256, 8) void k_logits_lse(
    const float* __restrict__ w_out, const float* __restrict__ b_out,
    const float* __restrict__ h, float* __restrict__ logits,
    float* __restrict__ pm, float* __restrict__ ps) {
    __shared__ float4 hs[256];
    __shared__ float sm[4], ss[4];
    const int tid = threadIdx.x;
    const int w = tid >> 6;
    const int lane = tid & 63;

    hs[tid] = reinterpret_cast<const float4*>(h)[tid];
    __syncthreads();

    const int wid = blockIdx.x * 4 + w;
    const float* wb = w_out + (size_t)wid * HH + lane * 4;
    float m = -1e30f, s = 0.0f;

#pragma unroll
    for (int k = 0; k < 3; ++k) {
        const int cA = 2 * k, cB = 2 * k + 1;
        const float* pa = wb + (size_t)cA * NWAVE * HH;
        const float* pb = wb + (size_t)cB * NWAVE * HH;
        float4 a0 = *reinterpret_cast<const float4*>(pa);
        float4 a1 = *reinterpret_cast<const float4*>(pa + 256);
        float4 a2 = *reinterpret_cast<const float4*>(pa + 512);
        float4 a3 = *reinterpret_cast<const float4*>(pa + 768);
        float4 b0 = *reinterpret_cast<const float4*>(pb);
        float4 b1 = *reinterpret_cast<const float4*>(pb + 256);
        float4 b2 = *reinterpret_cast<const float4*>(pb + 512);
        float4 b3 = *reinterpret_cast<const float4*>(pb + 768);
        float accA = dot4(a0, hs[lane]) + dot4(a1, hs[lane + 64]) +
                     dot4(a2, hs[lane + 128]) + dot4(a3, hs[lane + 192]);
        float accB = dot4(b0, hs[lane]) + dot4(b1, hs[lane + 64]) +
                     dot4(b2, hs[lane + 128]) + dot4(b3, hs[lane + 192]);
#pragma unroll
        for (int off = 1; off < 64; off <<= 1) {
            accA += __shfl_xor(accA, off, 64);
            accB += __shfl_xor(accB, off, 64);
        }
        const int rA = wid + cA * NWAVE;
        const int rB = wid + cB * NWAVE;
        const float vA = accA + b_out[rA];
        const float vB = accB + b_out[rB];
        if (lane == 0) {
            logits[rA] = vA;
            logits[rB] = vB;
        }
        float M = fmaxf(m, vA);
        s = s * __expf(m - M) + __expf(vA - M);
        m = M;
        M = fmaxf(m, vB);
        s = s * __expf(m - M) + __expf(vB - M);
        m = M;
    }
    if (wid < NTAIL) {
        const float* pt = wb + (size_t)6 * NWAVE * HH;
        float4 t0 = *reinterpret_cast<const float4*>(pt);
        float4 t1 = *reinterpret_cast<const float4*>(pt + 256);
        float4 t2 = *reinterpret_cast<const float4*>(pt + 512);
        float4 t3 = *reinterpret_cast<const float4*>(pt + 768);
        float acc = dot4(t0, hs[lane]) + dot4(t1, hs[lane + 64]) +
                    dot4(t2, hs[lane + 128]) + dot4(t3, hs[lane + 192]);
#pragma unroll
        for (int off = 1; off < 64; off <<= 1) acc += __shfl_xor(acc, off, 64);
        const int r = wid + 6 * NWAVE;
        const float v = acc + b_out[r];
        if (lane == 0) logits[r] = v;
        float M = fmaxf(m, v);
        s = s * __expf(m - M) + __expf(v - M);
        m = M;
    }

    if (lane == 0) { sm[w] = m; ss[w] = s; }
    __syncthreads();
    if (tid == 0) {
        float M = sm[0], S = ss[0];
#pragma unroll
        for (int q = 1; q < 4; ++q) lse_comb(M, S, sm[q], ss[q]);
        pm[blockIdx.x] = M;
        ps[blockIdx.x] = S;
    }
}

// Kernel 3: each block redundantly folds the NLB (m,s) pairs -> Z, then
// grid-strides out[v] = logits[v] - Z.
__global__ __launch_bounds__(256) void k_final(
    const float* __restrict__ logits, const float* __restrict__ pm,
    const float* __restrict__ ps, float* __restrict__ out) {
    __shared__ float sm[4], ss[4];
    __shared__ float sZ;
    int tid = threadIdx.x;
    int lane = tid & 63;
    float m = -1e30f, s = 0.0f;
#pragma unroll
    for (int t = 0; t < NLB / 256; ++t) {
        int p = tid + t * 256;
        lse_comb(m, s, pm[p], ps[p]);
    }
#pragma unroll
    for (int off = 1; off < 64; off <<= 1) {
        float om = __shfl_xor(m, off, 64);
        float os = __shfl_xor(s, off, 64);
        lse_comb(m, s, om, os);
    }
    if (lane == 0) { sm[tid >> 6] = m; ss[tid >> 6] = s; }
    __syncthreads();
    if (tid == 0) {
        float M = sm[0], S = ss[0];
#pragma unroll
        for (int q = 1; q < 4; ++q) lse_comb(M, S, sm[q], ss[q]);
        sZ = M + logf(S);
    }
    __syncthreads();
    float Z = sZ;
    for (int i = blockIdx.x * 256 + tid; i < VV; i += gridDim.x * 256)
        out[i] = logits[i] - Z;
}

extern "C" void kernel_launch(void* const* d_in, const int* in_sizes, int n_in,
                              void* d_out, int out_size, void* d_ws, size_t ws_size,
                              hipStream_t stream) {
    const int*   x     = (const int*)d_in[0];
    const float* h0    = (const float*)d_in[1];
    const float* c0    = (const float*)d_in[2];
    const float* emb   = (const float*)d_in[3];
    const float* w_ih  = (const float*)d_in[4];
    const float* w_hh  = (const float*)d_in[5];
    const float* b_ih  = (const float*)d_in[6];
    const float* b_hh  = (const float*)d_in[7];
    const float* w_out = (const float*)d_in[8];
    const float* b_out = (const float*)d_in[9];
    float* out = (float*)d_out;
    float* ws  = (float*)d_ws;

    float* logits = ws;             // 50257 floats (pad to 50304)
    float* pm     = ws + 50304;     // NLB floats
    float* ps     = pm + NLB;       // NLB floats

    k_gatecell<<<HH, 512, 0, stream>>>(x, emb, h0, c0, w_ih, w_hh, b_ih, b_hh, out);
    k_logits_lse<<<NLB, 256, 0, stream>>>(w_out, b_out, out + VV, logits, pm, ps);
    k_final<<<256, 256, 0, stream>>>(logits, pm, ps, out);
}

// Round 9
// 45.966 us; speedup vs baseline: 1.1337x; 1.0025x over previous
//
#include <hip/hip_runtime.h>
#include <math.h>

#define HH 1024
#define VV 50257
#define NLB 2048           // logits blocks
#define NWAVE (NLB * 4)    // 8192 logits waves
#define TBASE (6 * NWAVE)  // 49152; tail rows 49152..50256 (1105 rows)

__device__ __forceinline__ void lse_comb(float& m, float& s, float om, float os) {
    float M = fmaxf(m, om);
    s = s * __expf(m - M) + os * __expf(om - M);
    m = M;
}

__device__ __forceinline__ float sigmoidf(float x) { return 1.0f / (1.0f + __expf(-x)); }

__device__ __forceinline__ float dot4(float4 a, float4 b) {
    return a.x * b.x + a.y * b.y + a.z * b.z + a.w * b.w;
}

// Kernel 1: fused gates+cell. 1024 blocks x 512 threads (proven form).
__global__ __launch_bounds__(512) void k_gatecell(
    const int* __restrict__ x, const float* __restrict__ emb,
    const float* __restrict__ h0, const float* __restrict__ c0,
    const float* __restrict__ w_ih, const float* __restrict__ w_hh,
    const float* __restrict__ b_ih, const float* __restrict__ b_hh,
    float* __restrict__ out) {
    __shared__ float sg2[8];
    const int j = blockIdx.x;
    const int w = threadIdx.x >> 6;
    const int lane = threadIdx.x & 63;
    const int g = w >> 1, hf = w & 1;
    const int row = g * HH + j;
    const int base = hf * 512 + lane * 8;

    const float* e  = emb + (size_t)x[0] * HH + base;
    const float* wi = w_ih + (size_t)row * HH + base;
    const float* wh = w_hh + (size_t)row * HH + base;
    const float* hp = h0 + base;

    float4 wi0 = *reinterpret_cast<const float4*>(wi);
    float4 wi1 = *reinterpret_cast<const float4*>(wi + 4);
    float4 wh0 = *reinterpret_cast<const float4*>(wh);
    float4 wh1 = *reinterpret_cast<const float4*>(wh + 4);
    float4 e0  = *reinterpret_cast<const float4*>(e);
    float4 e1  = *reinterpret_cast<const float4*>(e + 4);
    float4 hv0 = *reinterpret_cast<const float4*>(hp);
    float4 hv1 = *reinterpret_cast<const float4*>(hp + 4);
    e0.x = fmaxf(e0.x, 0.f); e0.y = fmaxf(e0.y, 0.f);
    e0.z = fmaxf(e0.z, 0.f); e0.w = fmaxf(e0.w, 0.f);
    e1.x = fmaxf(e1.x, 0.f); e1.y = fmaxf(e1.y, 0.f);
    e1.z = fmaxf(e1.z, 0.f); e1.w = fmaxf(e1.w, 0.f);

    float acc = dot4(wi0, e0) + dot4(wi1, e1) + dot4(wh0, hv0) + dot4(wh1, hv1);
#pragma unroll
    for (int off = 1; off < 64; off <<= 1) acc += __shfl_xor(acc, off, 64);
    if (lane == 0)
        sg2[w] = acc + (hf == 0 ? b_ih[row] + b_hh[row] : 0.0f);
    __syncthreads();
    if (threadIdx.x == 0) {
        float ig = sigmoidf(sg2[0] + sg2[1]);
        float fg = sigmoidf(sg2[2] + sg2[3]);
        float gg = tanhf(sg2[4] + sg2[5]);
        float og = sigmoidf(sg2[6] + sg2[7]);
        float c = fg * c0[j] + ig * gg;
        float h = og * tanhf(c);
        out[VV + j] = h;
        out[VV + HH + j] = c;
    }
}

// Kernel 2: logits + fused per-block online LSE, HALF-WAVE row split:
// lanes 0-31 own row A, lanes 32-63 own row B. 8 load instrs per pair
// (1KB each), ONE 5-step xor reduce and ONE lanewise LSE update per pair.
__global__ __launch_bounds__(256, 8) void k_logits_lse(
    const float* __restrict__ w_out, const float* __restrict__ b_out,
    const float* __restrict__ h, float* __restrict__ logits,
    float* __restrict__ pm, float* __restrict__ ps) {
    __shared__ float4 hs4[256];
    __shared__ float sm[4], ss[4];
    const int tid = threadIdx.x;
    const int w = tid >> 6;
    const int lane = tid & 63;
    const int halfid = lane >> 5;   // 0: row A, 1: row B
    const int hl = lane & 31;

    hs4[tid] = reinterpret_cast<const float4*>(h)[tid];
    __syncthreads();

    const int wid = blockIdx.x * 4 + w;
    float m = -1e30f, s = 0.0f;

#pragma unroll
    for (int k = 0; k < 3; ++k) {
        const int r = wid + (2 * k + halfid) * NWAVE;   // my half's row
        const float* p = w_out + (size_t)r * HH + hl * 4;
        float acc = 0.0f;
#pragma unroll
        for (int j = 0; j < 8; ++j) {
            float4 wv = *reinterpret_cast<const float4*>(p + j * 128);
            acc += dot4(wv, hs4[hl + 32 * j]);
        }
#pragma unroll
        for (int off = 1; off < 32; off <<= 1) acc += __shfl_xor(acc, off, 64);
        const float v = acc + b_out[r];
        if (hl == 0) logits[r] = v;
        float M = fmaxf(m, v);            // branchless lanewise LSE
        s = s * __expf(m - M) + __expf(v - M);
        m = M;
    }
    // tail: rows TBASE..VV-1 (1105), two per wave on waves 0..552
    if (wid <= 552) {
        const int r = TBASE + 2 * wid + halfid;
        const bool valid = (r < VV);
        const int rc = valid ? r : (VV - 1);
        const float* p = w_out + (size_t)rc * HH + hl * 4;
        float acc = 0.0f;
#pragma unroll
        for (int j = 0; j < 8; ++j) {
            float4 wv = *reinterpret_cast<const float4*>(p + j * 128);
            acc += dot4(wv, hs4[hl + 32 * j]);
        }
#pragma unroll
        for (int off = 1; off < 32; off <<= 1) acc += __shfl_xor(acc, off, 64);
        float v = valid ? (acc + b_out[rc]) : -1e30f;
        if (hl == 0 && valid) logits[r] = v;
        float M = fmaxf(m, v);
        s = s * __expf(m - M) + __expf(v - M);
        m = M;
    }

    // merge the two halves (one cross-half combine), then block combine
    {
        float om = __shfl_xor(m, 32, 64);
        float os = __shfl_xor(s, 32, 64);
        lse_comb(m, s, om, os);
    }
    if (lane == 0) { sm[w] = m; ss[w] = s; }
    __syncthreads();
    if (tid == 0) {
        float M = sm[0], S = ss[0];
#pragma unroll
        for (int q = 1; q < 4; ++q) lse_comb(M, S, sm[q], ss[q]);
        pm[blockIdx.x] = M;
        ps[blockIdx.x] = S;
    }
}

// Kernel 3: each block redundantly folds the NLB (m,s) pairs -> Z, then
// grid-strides out[v] = logits[v] - Z.
__global__ __launch_bounds__(256) void k_final(
    const float* __restrict__ logits, const float* __restrict__ pm,
    const float* __restrict__ ps, float* __restrict__ out) {
    __shared__ float sm[4], ss[4];
    __shared__ float sZ;
    int tid = threadIdx.x;
    int lane = tid & 63;
    float m = -1e30f, s = 0.0f;
#pragma unroll
    for (int t = 0; t < NLB / 256; ++t) {
        int p = tid + t * 256;
        lse_comb(m, s, pm[p], ps[p]);
    }
#pragma unroll
    for (int off = 1; off < 64; off <<= 1) {
        float om = __shfl_xor(m, off, 64);
        float os = __shfl_xor(s, off, 64);
        lse_comb(m, s, om, os);
    }
    if (lane == 0) { sm[tid >> 6] = m; ss[tid >> 6] = s; }
    __syncthreads();
    if (tid == 0) {
        float M = sm[0], S = ss[0];
#pragma unroll
        for (int q = 1; q < 4; ++q) lse_comb(M, S, sm[q], ss[q]);
        sZ = M + logf(S);
    }
    __syncthreads();
    float Z = sZ;
    for (int i = blockIdx.x * 256 + tid; i < VV; i += gridDim.x * 256)
        out[i] = logits[i] - Z;
}

extern "C" void kernel_launch(void* const* d_in, const int* in_sizes, int n_in,
                              void* d_out, int out_size, void* d_ws, size_t ws_size,
                              hipStream_t stream) {
    const int*   x     = (const int*)d_in[0];
    const float* h0    = (const float*)d_in[1];
    const float* c0    = (const float*)d_in[2];
    const float* emb   = (const float*)d_in[3];
    const float* w_ih  = (const float*)d_in[4];
    const float* w_hh  = (const float*)d_in[5];
    const float* b_ih  = (const float*)d_in[6];
    const float* b_hh  = (const float*)d_in[7];
    const float* w_out = (const float*)d_in[8];
    const float* b_out = (const float*)d_in[9];
    float* out = (float*)d_out;
    float* ws  = (float*)d_ws;

    float* logits = ws;             // 50257 floats (pad to 50304)
    float* pm     = ws + 50304;     // NLB floats
    float* ps     = pm + NLB;       // NLB floats

    k_gatecell<<<HH, 512, 0, stream>>>(x, emb, h0, c0, w_ih, w_hh, b_ih, b_hh, out);
    k_logits_lse<<<NLB, 256, 0, stream>>>(w_out, b_out, out + VV, logits, pm, ps);
    k_final<<<256, 256, 0, stream>>>(logits, pm, ps, out);
}